// Round 15
// baseline (106.971 us; speedup 1.0000x reference)
//
#include <hip/hip_runtime.h>
#include <hip/hip_bf16.h>

// Deformable conv2d — NHWC-bf16 prepass + fused MFMA im2col, high-TLP variant.
// Tile 2x16 px, grid 2048 (8 blocks/CU), __launch_bounds__(256,8) (<=64 VGPR).
// ws: xt = NHWC bf16 (8 MB) | wp = bf16 [k][m][c] (72 KB)

constexpr int CI = 64, HI = 128, WI = 256;
constexpr int CO = 64, KK = 9, HO = 128, WO = 256;
constexpr int HWi = HI * WI;   // 32768
constexpr int HWo = HO * WO;   // 32768
constexpr int NPX = 32;        // px per tile (2 ho x 16 wo)

typedef __attribute__((ext_vector_type(4))) float f32x4;
typedef __attribute__((ext_vector_type(8))) short s16x8;
typedef __attribute__((ext_vector_type(4))) unsigned int u32x4;

__device__ __forceinline__ short to_bf16(float f) {
    __hip_bfloat16 h = __float2bfloat16(f);
    return *reinterpret_cast<short*>(&h);
}
__device__ __forceinline__ float bf2f(short s) {
    unsigned int u = ((unsigned int)(unsigned short)s) << 16;
    return __uint_as_float(u);
}

// ---- prepass: x NCHW fp32 -> NHWC bf16; blocks 0..143 also pack weights ----
__global__ __launch_bounds__(256, 2) void xpose(
    const float* __restrict__ x, short* __restrict__ xt,
    const float* __restrict__ w, short* __restrict__ wp)
{
    __shared__ short st[256 * 66];              // row stride 66 shorts (33 dw)
    const int tid = threadIdx.x;
    const int px0 = blockIdx.x * 256;           // global pixel (b*HWi + p)
    const int b = px0 >> 15;
    const float* xb = x + (size_t)b * CI * HWi + (px0 & (HWi - 1));
    #pragma unroll 8
    for (int c = 0; c < CI; ++c)
        st[tid * 66 + c] = to_bf16(xb[(size_t)c * HWi + tid]);   // coalesced read
    // weight packing folded in (blocks 0..143): wp[k][m][c]
    if (blockIdx.x < 144) {
        const int e = blockIdx.x * 256 + tid;   // < 36864 = 9*64*64
        const int k = e >> 12, rem = e & 4095;  // rem = m*64 + c
        wp[e] = to_bf16(w[(size_t)rem * KK + k]);
    }
    __syncthreads();
    const unsigned int* st32 = (const unsigned int*)st;
    #pragma unroll
    for (int r = 0; r < 4; ++r) {
        const int p = r * 64 + (tid >> 2), g = tid & 3;
        unsigned int v[8];
        #pragma unroll
        for (int j = 0; j < 8; ++j) v[j] = st32[p * 33 + g * 8 + j];
        unsigned int* dst = (unsigned int*)(xt + (size_t)(px0 + p) * 64 + g * 16);
        *(u32x4*)dst = u32x4{v[0], v[1], v[2], v[3]};
        *(u32x4*)(dst + 4) = u32x4{v[4], v[5], v[6], v[7]};      // coalesced write
    }
}

// ---- main: 32px x 64Cout tile, 9 k-chunks of K=64, bf16 MFMA, 8 blk/CU ----
__global__ __launch_bounds__(256, 8) void dconv_mfma(
    const short* __restrict__ xt, const float* __restrict__ off,
    const short* __restrict__ wp, const float* __restrict__ bias,
    float* __restrict__ out)
{
    __shared__ short sS[2][NPX * 64];           // dbuf [px][c] bf16, XOR-swizzled
    __shared__ float pw[4][KK * NPX];
    __shared__ int   pidx[4][KK * NPX];         // corner byte offset (NHWC)

    const int tid = threadIdx.x, lane = tid & 63, wv = tid >> 6;
    // XCD swizzle: 2048 = 8 XCDs x 256 contiguous tiles (bijective)
    const int wg = ((blockIdx.x & 7) << 8) | (blockIdx.x >> 3);
    const int b = wg >> 10, hot = (wg >> 4) & 63, wot = wg & 15;
    const int ho0 = hot * 2, wo0 = wot * 16;

    // phase 0: bilinear params for 9 taps x 32 px
    const float* offb = off + (size_t)b * (2 * KK * HWo);
    for (int e = tid; e < KK * NPX; e += 256) {
        const int k = e >> 5, n = e & 31;
        const int ho = ho0 + (n >> 4), wo = wo0 + (n & 15);
        const int ki = k / 3, kj = k - 3 * ki;
        const float oy = offb[(2 * k) * HWo + ho * WO + wo];
        const float ox = offb[(2 * k + 1) * HWo + ho * WO + wo];
        const float py  = (float)(ho - 1 + ki) + oy;
        const float pxx = (float)(wo - 1 + kj) + ox;
        const float y0f = floorf(py), x0f = floorf(pxx);
        const float wy = py - y0f, wx = pxx - x0f;
        const int y0 = (int)y0f, x0 = (int)x0f;
        const int y1 = y0 + 1, x1 = x0 + 1;
        const float vy0 = (y0 >= 0 && y0 < HI) ? 1.f : 0.f;
        const float vy1 = (y1 >= 0 && y1 < HI) ? 1.f : 0.f;
        const float vx0 = (x0 >= 0 && x0 < WI) ? 1.f : 0.f;
        const float vx1 = (x1 >= 0 && x1 < WI) ? 1.f : 0.f;
        const int cy0 = min(max(y0, 0), HI - 1), cy1 = min(max(y1, 0), HI - 1);
        const int cx0 = min(max(x0, 0), WI - 1), cx1 = min(max(x1, 0), WI - 1);
        pw[0][e] = (1.f - wy) * (1.f - wx) * vy0 * vx0;
        pw[1][e] = (1.f - wy) * wx         * vy0 * vx1;
        pw[2][e] = wy         * (1.f - wx) * vy1 * vx0;
        pw[3][e] = wy         * wx         * vy1 * vx1;
        pidx[0][e] = (cy0 * WI + cx0) * 128;    // *64ch*2B
        pidx[1][e] = (cy0 * WI + cx1) * 128;
        pidx[2][e] = (cy1 * WI + cx0) * 128;
        pidx[3][e] = (cy1 * WI + cx1) * 128;
    }

    f32x4 acc[2];
    {
        const int r0 = 16 * wv + 4 * (lane >> 4);
        const f32x4 ini = *(const f32x4*)(bias + r0);
        acc[0] = ini; acc[1] = ini;
    }
    __syncthreads();                            // pw/pidx ready

    const char* xtb = (const char*)xt + (size_t)b * HWi * 128;
    const int px = tid >> 3, cb = (tid & 7) * 16;   // 8 thr/px, 8 ch (16B) each
    const int mrow = 16 * wv + (lane & 15);
    const int ke = 8 * (lane >> 4);             // element offset into K-slice
    const int koffb = 16 * (lane >> 4);         // byte offset for B-frag reads
    const int xr = (lane & 7) << 4;
    const int swz = (px * 128 + cb) ^ ((px & 7) << 4);

    int p = 0;
    for (int k = 0; k < KK; ++k) {
        // ---- sample: 4 corner loads (full-line coalesced per 8 lanes) ----
        const int e = k * NPX + px;
        const s16x8 u0 = *(const s16x8*)(xtb + pidx[0][e] + cb);
        const s16x8 u1 = *(const s16x8*)(xtb + pidx[1][e] + cb);
        const s16x8 u2 = *(const s16x8*)(xtb + pidx[2][e] + cb);
        const s16x8 u3 = *(const s16x8*)(xtb + pidx[3][e] + cb);
        const float w0 = pw[0][e], w1 = pw[1][e], w2 = pw[2][e], w3 = pw[3][e];
        s16x8 v;
        #pragma unroll
        for (int j = 0; j < 8; ++j) {
            float s = w0 * bf2f(u0[j]);
            s = fmaf(w1, bf2f(u1[j]), s);
            s = fmaf(w2, bf2f(u2[j]), s);
            s = fmaf(w3, bf2f(u3[j]), s);
            v[j] = to_bf16(s);
        }
        *(s16x8*)((char*)sS[p] + swz) = v;

        // A-frags for this chunk from packed global (L2-resident)
        const short* wpk = wp + k * 4096;
        const s16x8 a0 = *(const s16x8*)(wpk + mrow * 64 + ke);
        const s16x8 a1 = *(const s16x8*)(wpk + mrow * 64 + 32 + ke);
        __syncthreads();                        // sS[p] ready

        // ---- MFMA: 2 N-frags x 2 K-steps from sS[p] ----
        const char* spc = (const char*)sS[p];
        #pragma unroll
        for (int f = 0; f < 2; ++f) {
            const int nrow = 16 * f + (lane & 15);
            const s16x8 b0 = *(const s16x8*)(spc + ((nrow * 128 + koffb) ^ xr));
            const s16x8 b1 = *(const s16x8*)(spc + ((nrow * 128 + 64 + koffb) ^ xr));
            acc[f] = __builtin_amdgcn_mfma_f32_16x16x32_bf16(a0, b0, acc[f], 0, 0, 0);
            acc[f] = __builtin_amdgcn_mfma_f32_16x16x32_bf16(a1, b1, acc[f], 0, 0, 0);
        }
        p ^= 1;                                 // dbuf: next write other buf
    }

    #pragma unroll
    for (int f = 0; f < 2; ++f) {
        const int ho = ho0 + f;
        const int wo = wo0 + (lane & 15);
        const int m0 = 16 * wv + 4 * (lane >> 4);
        float* po = out + (((size_t)(b * CO + m0) * HO + ho) * WO + wo);
        #pragma unroll
        for (int r = 0; r < 4; ++r)
            po[(size_t)r * HWo] = acc[f][r];
    }
}

extern "C" void kernel_launch(void* const* d_in, const int* in_sizes, int n_in,
                              void* d_out, int out_size, void* d_ws, size_t ws_size,
                              hipStream_t stream) {
    const float* x    = (const float*)d_in[0];
    const float* off  = (const float*)d_in[1];
    const float* wgt  = (const float*)d_in[2];
    const float* bias = (const float*)d_in[3];
    float* out = (float*)d_out;
    short* xt = (short*)d_ws;                                   // 8 MB
    short* wp = (short*)((char*)d_ws + (size_t)2 * HWi * 64 * 2);
    xpose<<<dim3(256), dim3(256), 0, stream>>>(x, xt, wgt, wp);
    dconv_mfma<<<dim3(2048), dim3(256), 0, stream>>>(xt, off, wp, bias, out);
}